// Round 11
// baseline (120.571 us; speedup 1.0000x reference)
//
#include <hip/hip_runtime.h>
#include <hip/hip_bf16.h>

typedef unsigned short u16;
typedef __bf16 bf16x8 __attribute__((ext_vector_type(8)));
typedef float f32x4 __attribute__((ext_vector_type(4)));

typedef const __attribute__((address_space(1))) void gv_t;
typedef __attribute__((address_space(3))) void lv_t;

#define NN 2048
#define DD 1024
#define SS 49
#define CC 1000
#define CP 1024

#define BK 64
#define KK DD
#define NT (KK / BK)   // 16 K-steps

__device__ inline u16 f2bf(float f) {
    __hip_bfloat16 h = __float2bfloat16(f);
    union { __hip_bfloat16 h; u16 u; } cv; cv.h = h; return cv.u;
}

// ---- 64x64 MFMA GEMM core: 2-phase double-buffer, 32KB LDS (r3/r6 core) ----
__device__ __forceinline__ void gemm64_core(const u16* __restrict__ A,
                                            const u16* __restrict__ Bt,
                                            int m0, int n0, char* smem,
                                            f32x4 acc[2][2], int tid) {
    char* As = smem;            // [2][8192]
    char* Bs = smem + 16384;    // [2][8192]
    const int lane = tid & 63;
    const int wr = (tid >> 6) >> 1, wc = (tid >> 6) & 1;
    const int r16 = lane & 15, hk = lane >> 4;
    const char* Ab = (const char*)A;
    const char* Bb = (const char*)Bt;

    auto stage = [&](int buf, int k0) {
        #pragma unroll
        for (int j = 0; j < 2; j++) {
            const int c = j * 256 + tid;
            const int row = c >> 3, slot = c & 7;
            const int goff = ((slot ^ (row & 7)) << 4);
            __builtin_amdgcn_global_load_lds(
                (gv_t*)(Ab + ((size_t)(m0 + row) * KK + k0) * 2 + goff),
                (lv_t*)(As + buf * 8192 + c * 16), 16, 0, 0);
            __builtin_amdgcn_global_load_lds(
                (gv_t*)(Bb + ((size_t)(n0 + row) * KK + k0) * 2 + goff),
                (lv_t*)(Bs + buf * 8192 + c * 16), 16, 0, 0);
        }
    };

    stage(0, 0);
    __syncthreads();
    int cur = 0;
    for (int t = 0; t < NT; ++t) {
        if (t + 1 < NT) stage(cur ^ 1, (t + 1) * BK);
        bf16x8 a[2][2], b[2][2];
        #pragma unroll
        for (int mi = 0; mi < 2; mi++) {
            const int row = wr * 32 + mi * 16 + r16;
            #pragma unroll
            for (int kk2 = 0; kk2 < 2; kk2++) {
                const int g = kk2 * 4 + hk;
                a[mi][kk2] = *(const bf16x8*)(As + cur * 8192 + row * 128 + ((g ^ (row & 7)) << 4));
            }
        }
        #pragma unroll
        for (int ni = 0; ni < 2; ni++) {
            const int row = wc * 32 + ni * 16 + r16;
            #pragma unroll
            for (int kk2 = 0; kk2 < 2; kk2++) {
                const int g = kk2 * 4 + hk;
                b[ni][kk2] = *(const bf16x8*)(Bs + cur * 8192 + row * 128 + ((g ^ (row & 7)) << 4));
            }
        }
        #pragma unroll
        for (int kk2 = 0; kk2 < 2; kk2++)
            #pragma unroll
            for (int mi = 0; mi < 2; mi++)
                #pragma unroll
                for (int ni = 0; ni < 2; ni++)
                    acc[mi][ni] = __builtin_amdgcn_mfma_f32_16x16x32_bf16(
                        a[mi][kk2], b[ni][kk2], acc[mi][ni], 0, 0, 0);
        __syncthreads();
        cur ^= 1;
    }
}

// ---- L0: prep via LDS tile transpose (r10, coalesced P^T) ------------------
__global__ __launch_bounds__(256) void prep_k(const float* __restrict__ P,
                                              const float* __restrict__ mu,
                                              u16* __restrict__ q,
                                              u16* __restrict__ mu_bf,
                                              float* __restrict__ qzh,
                                              float* __restrict__ qmuh) {
    __shared__ float t1[64][65];
    __shared__ float t2[64][65];
    const int tid = threadIdx.x, bid = blockIdx.x;
    const int br = bid >> 4, bc = bid & 15;
    const int br64 = br * 64, bc64 = bc * 64;

    #pragma unroll
    for (int it = 0; it < 16; it++) {
        const int idx = it * 256 + tid;
        const int row = idx >> 6, col = idx & 63;
        t1[row][col] = P[(size_t)(br64 + row) * DD + bc64 + col];
        t2[row][col] = P[(size_t)(bc64 + row) * DD + br64 + col];
    }
    __syncthreads();
    #pragma unroll
    for (int it = 0; it < 16; it++) {
        const int idx = it * 256 + tid;
        const int row = idx >> 6, col = idx & 63;
        q[(size_t)(br64 + row) * DD + bc64 + col] = f2bf(t1[row][col] + t2[col][row]);
    }

    const size_t base = (size_t)bid * 4096;
    #pragma unroll
    for (int it = 0; it < 16; it++) {
        const size_t j = base + it * 256 + tid;
        const int r = (int)(j >> 10);
        mu_bf[j] = f2bf(r < CC ? mu[j] : 0.f);
    }
    const int g = bid * 256 + tid;
    if (g < NN) qzh[g]  = 0.f;
    if (g < CP) qmuh[g] = 0.f;
}

// ---- L1: muQ GEMM (256 blocks, first) + pool (8192 blocks) — r10 verified --
__global__ __launch_bounds__(256) void pool_muq_k(const float* __restrict__ x,
                                                  const u16* __restrict__ q,
                                                  const u16* __restrict__ mu_bf,
                                                  const float* __restrict__ mu,
                                                  u16* __restrict__ b_bf,
                                                  float* __restrict__ qmuh,
                                                  float* __restrict__ zf,
                                                  u16* __restrict__ zb) {
    __shared__ char smem[50176];   // pool: float[12544]; gemm: 2x16KB dbuf
    const int tid = threadIdx.x;
    const int bid = blockIdx.x;

    if (bid >= 256) {
        const int u = bid - 256;
        float* lds = (float*)smem;
        const size_t base = (size_t)u * (256 * SS);
        const float4* src = (const float4*)(x + base);
        float4* dst = (float4*)lds;
        #pragma unroll
        for (int i = 0; i < 13; i++) {
            int idx = i * 256 + tid;
            if (idx < (256 * SS) / 4) dst[idx] = src[idx];
        }
        __syncthreads();
        const float* r = lds + tid * SS;
        float s = 0.f;
        #pragma unroll
        for (int j = 0; j < SS; j++) s += r[j];
        s *= (1.f / 49.f);
        size_t o = (size_t)u * 256 + tid;
        zf[o] = s;
        zb[o] = f2bf(s);
        return;
    }

    const int m0 = (bid >> 4) * 64, n0 = (bid & 15) * 64;
    f32x4 acc[2][2] = {};
    gemm64_core(mu_bf, q, m0, n0, smem, acc, tid);

    const int lane = tid & 63;
    const int wr = (tid >> 6) >> 1, wc = (tid >> 6) & 1;
    const int cr = (lane >> 4) * 4, cc2 = lane & 15;
    #pragma unroll
    for (int mi = 0; mi < 2; mi++) {
        const int gr0 = m0 + wr * 32 + mi * 16 + cr;
        #pragma unroll
        for (int r = 0; r < 4; r++) {
            const int row = gr0 + r;
            float v = 0.f;
            #pragma unroll
            for (int ni = 0; ni < 2; ni++) {
                const int gc = n0 + wc * 32 + ni * 16 + cc2;
                float av = acc[mi][ni][r];
                float sv = (row < CC) ? mu[(size_t)row * DD + gc] : 0.f;
                v += av * sv;
                b_bf[(size_t)row * DD + gc] = f2bf(av);
            }
            #pragma unroll
            for (int m = 1; m < 16; m <<= 1) v += __shfl_xor(v, m);
            if (cc2 == 0) atomicAdd(qmuh + row, 0.25f * v);
        }
    }
}

// ---- L2: FUSED zQ-diag + score, dual-B GEMM (512 blocks) -------------------
// Tile (m,j): A = z rows [64m,64m+64) staged ONCE; two B streams: Bq = q rows
// [64j,..) (for zQ-diag) and Bb = b_bf rows [64j,..) (for score). Per K-step:
// 24KB staged (vs 32KB across the two old kernels, -25% L3 traffic, A-panel
// read once) and 16 MFMA/wave/step against one barrier pair (2x the stall
// amortization of the separate kernels). Epilogue does both jobs.
__global__ __launch_bounds__(256) void zscore_k(const u16* __restrict__ z_bf,
                                                const u16* __restrict__ q,
                                                const u16* __restrict__ b_bf,
                                                const float* __restrict__ zf,
                                                float* __restrict__ qzh,
                                                const float* __restrict__ qmuh,
                                                float* __restrict__ out) {
    __shared__ char smem[49152];   // As[2][8K] | Bq[2][8K] | Bb[2][8K]
    const int tid = threadIdx.x, bid = blockIdx.x;
    const int m0 = (bid >> 4) * 64, n0 = (bid & 15) * 64;
    const int lane = tid & 63;
    const int wr = (tid >> 6) >> 1, wc = (tid >> 6) & 1;
    const int r16 = lane & 15, hk = lane >> 4;
    char* As = smem;
    char* Bq = smem + 16384;
    char* Bb = smem + 32768;
    const char* Ap = (const char*)z_bf;
    const char* Qp = (const char*)q;
    const char* Bp = (const char*)b_bf;

    f32x4 accS[2][2] = {};   // score (vs b_bf)
    f32x4 accZ[2][2] = {};   // zQ-diag (vs q)

    auto stage = [&](int buf, int k0) {
        #pragma unroll
        for (int j = 0; j < 2; j++) {
            const int c = j * 256 + tid;
            const int row = c >> 3, slot = c & 7;
            const int goff = ((slot ^ (row & 7)) << 4);
            const size_t ao = ((size_t)(m0 + row) * KK + k0) * 2 + goff;
            const size_t bo = ((size_t)(n0 + row) * KK + k0) * 2 + goff;
            __builtin_amdgcn_global_load_lds((gv_t*)(Ap + ao),
                (lv_t*)(As + buf * 8192 + c * 16), 16, 0, 0);
            __builtin_amdgcn_global_load_lds((gv_t*)(Qp + bo),
                (lv_t*)(Bq + buf * 8192 + c * 16), 16, 0, 0);
            __builtin_amdgcn_global_load_lds((gv_t*)(Bp + bo),
                (lv_t*)(Bb + buf * 8192 + c * 16), 16, 0, 0);
        }
    };

    stage(0, 0);
    __syncthreads();
    int cur = 0;
    for (int t = 0; t < NT; ++t) {
        if (t + 1 < NT) stage(cur ^ 1, (t + 1) * BK);
        bf16x8 a[2][2], bq[2][2], bb[2][2];
        #pragma unroll
        for (int mi = 0; mi < 2; mi++) {
            const int row = wr * 32 + mi * 16 + r16;
            #pragma unroll
            for (int kk2 = 0; kk2 < 2; kk2++) {
                const int g = kk2 * 4 + hk;
                a[mi][kk2] = *(const bf16x8*)(As + cur * 8192 + row * 128 + ((g ^ (row & 7)) << 4));
            }
        }
        #pragma unroll
        for (int ni = 0; ni < 2; ni++) {
            const int row = wc * 32 + ni * 16 + r16;
            #pragma unroll
            for (int kk2 = 0; kk2 < 2; kk2++) {
                const int g = kk2 * 4 + hk;
                const int off = row * 128 + ((g ^ (row & 7)) << 4);
                bq[ni][kk2] = *(const bf16x8*)(Bq + cur * 8192 + off);
                bb[ni][kk2] = *(const bf16x8*)(Bb + cur * 8192 + off);
            }
        }
        #pragma unroll
        for (int kk2 = 0; kk2 < 2; kk2++)
            #pragma unroll
            for (int mi = 0; mi < 2; mi++)
                #pragma unroll
                for (int ni = 0; ni < 2; ni++) {
                    accS[mi][ni] = __builtin_amdgcn_mfma_f32_16x16x32_bf16(
                        a[mi][kk2], bb[ni][kk2], accS[mi][ni], 0, 0, 0);
                    accZ[mi][ni] = __builtin_amdgcn_mfma_f32_16x16x32_bf16(
                        a[mi][kk2], bq[ni][kk2], accZ[mi][ni], 0, 0, 0);
                }
        __syncthreads();
        cur ^= 1;
    }

    // epilogue: C/D layout col=lane&15, row=(lane>>4)*4+r
    const int cr = hk * 4, cc2 = r16;
    // (a) zQ-diag partials -> qzh atomics
    #pragma unroll
    for (int mi = 0; mi < 2; mi++) {
        const int gr0 = m0 + wr * 32 + mi * 16 + cr;
        #pragma unroll
        for (int r = 0; r < 4; r++) {
            const int row = gr0 + r;
            float v = 0.f;
            #pragma unroll
            for (int ni = 0; ni < 2; ni++) {
                const int gc = n0 + wc * 32 + ni * 16 + cc2;
                v += accZ[mi][ni][r] * zf[(size_t)row * DD + gc];
            }
            #pragma unroll
            for (int m = 1; m < 16; m <<= 1) v += __shfl_xor(v, m);
            if (cc2 == 0) atomicAdd(qzh + row, 0.25f * v);
        }
    }
    // (b) score-partial -> out (qzh subtracted by L3 fixup)
    #pragma unroll
    for (int mi = 0; mi < 2; mi++) {
        #pragma unroll
        for (int ni = 0; ni < 2; ni++) {
            const int gr = m0 + wr * 32 + mi * 16 + cr;
            const int gc = n0 + wc * 32 + ni * 16 + cc2;
            if (gc < CC) {
                const float qm = qmuh[gc];
                #pragma unroll
                for (int r = 0; r < 4; r++)
                    out[(size_t)(gr + r) * CC + gc] =
                        0.5f * accS[mi][ni][r] - qm;
            }
        }
    }
}

// ---- L3: in-place fixup out[n,c] -= qzh[n] ---------------------------------
__global__ __launch_bounds__(256) void fixup_k(float* __restrict__ out,
                                               const float* __restrict__ qzh) {
    const int n = blockIdx.x, tid = threadIdx.x;
    if (tid >= 250) return;
    const float qz = qzh[n];
    float4* p = (float4*)(out + (size_t)n * CC + tid * 4);
    float4 v = *p;
    v.x -= qz; v.y -= qz; v.z -= qz; v.w -= qz;
    *p = v;
}

extern "C" void kernel_launch(void* const* d_in, const int* in_sizes, int n_in,
                              void* d_out, int out_size, void* d_ws, size_t ws_size,
                              hipStream_t stream) {
    const float* x  = (const float*)d_in[0];   // [N, D, S]
    const float* mu = (const float*)d_in[1];   // [C, D]
    const float* P  = (const float*)d_in[2];   // [D, D]
    float* out = (float*)d_out;                // [N, C]

    // workspace carve (~18.3 MB)
    char* w = (char*)d_ws;
    u16*   q_bf  = (u16*)w;   w += (size_t)DD * DD * 2;   // 2 MB
    u16*   mu_bf = (u16*)w;   w += (size_t)CP * DD * 2;   // 2 MB
    u16*   b_bf  = (u16*)w;   w += (size_t)CP * DD * 2;   // 2 MB
    u16*   z_bf  = (u16*)w;   w += (size_t)NN * DD * 2;   // 4 MB
    float* zf    = (float*)w; w += (size_t)NN * DD * 4;   // 8 MB
    float* qzh   = (float*)w; w += (size_t)NN * 4;
    float* qmuh  = (float*)w;

    // L0: prep (coalesced P^T via LDS transpose) + mu cast + zeroing
    prep_k<<<256, 256, 0, stream>>>(P, mu, q_bf, mu_bf, qzh, qmuh);
    // L1: muQ (256, first) + pool (8192)
    pool_muq_k<<<256 + (NN * DD) / 256, 256, 0, stream>>>(
        x, q_bf, mu_bf, mu, b_bf, qmuh, zf, z_bf);
    // L2: fused zQ-diag + score (512 dual-B blocks) -> out (minus qmuh only)
    zscore_k<<<512, 256, 0, stream>>>(z_bf, q_bf, b_bf, zf, qzh, qmuh, out);
    // L3: out[n,:] -= qzh[n] in place
    fixup_k<<<NN, 256, 0, stream>>>(out, qzh);
}